// Round 11
// baseline (302.701 us; speedup 1.0000x reference)
//
#include <hip/hip_runtime.h>
#include <hip/hip_bf16.h>

typedef unsigned short u16;
typedef unsigned int   u32;
typedef short  s16x8 __attribute__((ext_vector_type(8)));
typedef float  f32x4 __attribute__((ext_vector_type(4)));

#define B_   8
#define N_   1025
#define H_   12
#define D_   64
#define C_   768
#define NB_  8
#define M_   (B_*N_)     // 8200
#define QKV_ (3*C_)      // 2304
#define NEGI -30000.0f
#define LOG2E 1.44269504089f
#define SHIFT2 11.5415603271f   // 8 * log2(e); softmax shift in exp2 units
#define CS_  1088        // cidx padded rows/stride (17*64)

__device__ __forceinline__ float bf2f(u16 u) {
    unsigned int i = ((unsigned int)u) << 16;
    float f; __builtin_memcpy(&f, &i, 4); return f;
}
// native HW RNE f32->bf16 (m240: scalar cast lowers to v_cvt, 1 op vs 4)
__device__ __forceinline__ u16 f2bf(float f) {
    __hip_bfloat16 h = __float2bfloat16(f);
    u16 u; __builtin_memcpy(&u, &h, 2); return u;
}
__device__ __forceinline__ float exp2fast(float x) {
#if __has_builtin(__builtin_amdgcn_exp2f)
    return __builtin_amdgcn_exp2f(x);
#else
    float r; asm("v_exp_f32 %0, %1" : "=v"(r) : "v"(x)); return r;
#endif
}

// global -> LDS direct DMA, 16B per lane. lptr must be wave-uniform; HW
// writes lane's 16B at lptr + lane*16. gptr is per-lane.
__device__ __forceinline__ void gload_lds16(const u16* gptr, u16* lptr) {
    __builtin_amdgcn_global_load_lds(
        (const __attribute__((address_space(1))) void*)gptr,
        (__attribute__((address_space(3))) void*)lptr, 16, 0, 0);
}

// ---------------------------------------------------------------------------
// One-shot fp32 -> bf16 (RNE).
// ---------------------------------------------------------------------------
__global__ __launch_bounds__(256)
void cvt_f32_bf16(const float* __restrict__ a, u16* __restrict__ oa, long na,
                  const float* __restrict__ b, u16* __restrict__ ob, long nb,
                  const float* __restrict__ c, u16* __restrict__ oc, long nc)
{
    long t = ((long)blockIdx.x * 256 + threadIdx.x) * 8;
    const float* s; u16* d; long off;
    if (t < na)                 { s = a; d = oa; off = t; }
    else if (t < na + nb)       { s = b; d = ob; off = t - na; }
    else if (t < na + nb + nc)  { s = c; d = oc; off = t - na - nb; }
    else return;
    float4 f0 = *reinterpret_cast<const float4*>(s + off);
    float4 f1 = *reinterpret_cast<const float4*>(s + off + 4);
    u16 tmp[8] = { f2bf(f0.x), f2bf(f0.y), f2bf(f0.z), f2bf(f0.w),
                   f2bf(f1.x), f2bf(f1.y), f2bf(f1.z), f2bf(f1.w) };
    *reinterpret_cast<uint4*>(d + off) = *reinterpret_cast<uint4*>(tmp);
}

// Packed+permuted bucket table: byte at [i][jt*64 + 4*l + bn] = brow*8+bcol for
// j = jt*64 + bn*16 + l.
__global__ void build_cidx(const int* __restrict__ brow, const int* __restrict__ bcol,
                           unsigned char* __restrict__ cidx) {
    long t = (long)blockIdx.x * 256 + threadIdx.x;
    const long total = (long)CS_ * (CS_ / 4);
    if (t >= total) return;
    int i = (int)(t / (CS_ / 4));
    int k = (int)(t % (CS_ / 4));
    u32 w = 0;
    int p0 = k * 4;
    #pragma unroll
    for (int bnb = 0; bnb < 4; ++bnb) {
        int p = p0 + bnb;
        int jt = p >> 6, rem = p & 63;
        int l = rem >> 2, bn = rem & 3;
        int j = jt * 64 + bn * 16 + l;
        u32 c = 63u;
        if (i < N_ && j < N_) {
            u32 br = (u32)(brow[(size_t)i * N_ + j] & 7);
            u32 bc = (u32)(bcol[(size_t)i * N_ + j] & 7);
            c = (br << 3) | bc;
        }
        w |= c << (8 * bnb);
    }
    ((u32*)cidx)[t] = w;
}

// ---------------------------------------------------------------------------
// GEMM: Cout[M,Nn](ldc) = A[M,K](lda) @ Bt[Nn,K]^T + bias. bf16 operands.
// BK=64, LDS [128][64] staged via global_load_lds with pre-swizzled global
// source columns; swizzled fragment reads (2-way max bank aliasing).
// (Proven R10 kernel, unchanged.)
// ---------------------------------------------------------------------------
template<int OF32>
__global__ __launch_bounds__(256)
void gemm_bt(const u16* __restrict__ Ap, int lda,
             const u16* __restrict__ Btp,
             const float* __restrict__ bias,
             void* __restrict__ Cout, int ldc,
             int M, int Nn, int K, int scale_cols, float scale_val)
{
    __shared__ u16 As[128][64];
    __shared__ u16 Bs[128][64];
    const int tid  = threadIdx.x;
    const int lane = tid & 63;
    const int wave = tid >> 6;
    const int wm = (wave >> 1) * 64;
    const int wn = (wave & 1) * 64;
    const int m0 = blockIdx.y * 128;
    const int n0 = blockIdx.x * 128;

    const int srow = wave * 32 + (lane >> 3);
    const int gcol = (((lane & 7) ^ ((lane >> 3) & 7))) * 8;   // pre-swizzled

    f32x4 acc[4][4] = {};

    for (int k0 = 0; k0 < K; k0 += 64) {
        __syncthreads();
        #pragma unroll
        for (int i = 0; i < 4; ++i) {
            int ar = m0 + srow + i * 8;
            if (ar > M - 1) ar = M - 1;                    // clamp (valid addr)
            gload_lds16(Ap + (size_t)ar * lda + k0 + gcol, &As[wave * 32 + i * 8][0]);
            int br = n0 + srow + i * 8;                    // Nn % 128 == 0
            gload_lds16(Btp + (size_t)br * K + k0 + gcol,  &Bs[wave * 32 + i * 8][0]);
        }
        __syncthreads();

        #pragma unroll
        for (int kk = 0; kk < 2; ++kk) {
            const int kc = ((kk * 4 + (lane >> 4)) ^ (lane & 7)) << 3;  // swizzled read col
            s16x8 af[4], bfv[4];
            #pragma unroll
            for (int qq = 0; qq < 4; ++qq) {
                af[qq]  = *reinterpret_cast<const s16x8*>(&As[wm + qq*16 + (lane & 15)][kc]);
                bfv[qq] = *reinterpret_cast<const s16x8*>(&Bs[wn + qq*16 + (lane & 15)][kc]);
            }
            #pragma unroll
            for (int bm = 0; bm < 4; ++bm)
                #pragma unroll
                for (int bn = 0; bn < 4; ++bn)
                    acc[bm][bn] = __builtin_amdgcn_mfma_f32_16x16x32_bf16(af[bm], bfv[bn], acc[bm][bn], 0, 0, 0);
        }
    }

    #pragma unroll
    for (int bm = 0; bm < 4; ++bm) {
        #pragma unroll
        for (int bn = 0; bn < 4; ++bn) {
            int col = n0 + wn + bn*16 + (lane & 15);
            float bv = bias[col];
            float sc = (col < scale_cols) ? scale_val : 1.0f;
            #pragma unroll
            for (int r = 0; r < 4; ++r) {
                int row = m0 + wm + bm*16 + (lane >> 4)*4 + r;
                if (row < M) {
                    float v = (acc[bm][bn][r] + bv) * sc;
                    size_t idx = (size_t)row * ldc + col;
                    if (OF32) ((float*)Cout)[idx] = v;
                    else      ((u16*)Cout)[idx]   = f2bf(v);
                }
            }
        }
    }
}

// ---------------------------------------------------------------------------
// MFMA flash attention — 8 waves / 128 Q-rows per block, KVBLK=64.
// LOAD PLACEMENT (this round): hipcc drains vmcnt(0) before every s_barrier,
// so loads issued right before a barrier get zero latency cover. Reorder:
//   barrier1 -> commit(kpre/vpre) -> barrier2 -> cpk(t) loads (covered by
//   QK MFMAs) -> QK^T -> prefetch(t+1) (covered by SMAX+PV; drained at next
//   tile's barrier1) -> SMAX/PV.
// kpre/vpre are dead after the commit ds_writes, so the post-barrier2
// overwrite is safe. qtCombF padded to [128][68] (rows de-aligned by 4
// banks per row -> fewer f32-gather conflicts).
// __launch_bounds__(512,4): 2 blocks/CU (R8: residency > spill).
// ---------------------------------------------------------------------------
__global__ __launch_bounds__(512, 4)
void flash_kernel(const u16* __restrict__ qkv,
                  const float* __restrict__ rpe_r, const float* __restrict__ rpe_c,
                  const unsigned char* __restrict__ cidx,
                  u16* __restrict__ aout)
{
    __shared__ u16 Ks[64][72];       // [j][d]                       9216 B
    __shared__ u16 Vt[64][72];       // [d][swz(j)]                  9216 B
    __shared__ u16 Ps[8][16][72];    // [wave][i][swz(j)]           18432 B
    __shared__ float qtCombF[128][68]; // [row][u*8+v] f32, +4 pad  34816 B
    // total 71680 B/block -> 2 blocks/CU

    const int tid  = threadIdx.x;
    const int lane = tid & 63;
    const int wave = tid >> 6;       // 0..7
    const int q    = lane >> 4;      // 0..3
    const int l    = lane & 15;
    const int bh = blockIdx.y;
    const int b = bh / H_;
    const int h = bh % H_;
    const int i0 = blockIdx.x * 128;

    float* qtrA = (float*)&Ps[0][0][0];   // [128][8] (aliased, prologue only)
    float* qtcA = qtrA + 128 * 8;         // [128][8]

    // ---- phase A: per-row qt projections (row=t>>2, u={2*(t&3),+1}), streaming
    {
        int row = tid >> 2;              // 0..127
        int u0  = (tid & 3) * 2;
        int ig = i0 + row;
        bool valid = ig < N_;
        const u16* qrow = &qkv[(size_t)(b * N_ + (valid ? ig : 0)) * QKV_ + h * D_];
        #pragma unroll
        for (int uu = 0; uu < 2; ++uu) {
            int u = u0 + uu;
            const float4* rr4 = (const float4*)&rpe_r[(size_t)(h * NB_ + u) * D_];
            const float4* rc4 = (const float4*)&rpe_c[(size_t)(h * NB_ + u) * D_];
            float sr = 0.f, sc = 0.f;
            #pragma unroll
            for (int e2 = 0; e2 < 8; ++e2) {
                uint4 t = *reinterpret_cast<const uint4*>(&qrow[e2 * 8]);
                s16x8 q8 = *reinterpret_cast<s16x8*>(&t);
                float4 a0 = rr4[2*e2], a1 = rr4[2*e2+1];
                float4 c0 = rc4[2*e2], c1 = rc4[2*e2+1];
                float f0 = bf2f((u16)q8[0]), f1 = bf2f((u16)q8[1]);
                float f2 = bf2f((u16)q8[2]), f3 = bf2f((u16)q8[3]);
                float f4 = bf2f((u16)q8[4]), f5 = bf2f((u16)q8[5]);
                float f6 = bf2f((u16)q8[6]), f7 = bf2f((u16)q8[7]);
                sr += f0*a0.x + f1*a0.y + f2*a0.z + f3*a0.w
                    + f4*a1.x + f5*a1.y + f6*a1.z + f7*a1.w;
                sc += f0*c0.x + f1*c0.y + f2*c0.z + f3*c0.w
                    + f4*c1.x + f5*c1.y + f6*c1.z + f7*c1.w;
            }
            qtrA[row*8 + u] = valid ? sr : 0.f;
            qtcA[row*8 + u] = valid ? sc : 0.f;
        }
    }
    __syncthreads();
    // ---- phase B: qtCombF[row][u*8+v] = qtr[u]+qtc[v] (f32)
    {
        int row = tid >> 2;
        int c0  = (tid & 3) * 16;
        float tmp[16];
        #pragma unroll
        for (int cc = 0; cc < 16; ++cc) {
            int c = c0 + cc;
            tmp[cc] = qtrA[row*8 + (c >> 3)] + qtcA[row*8 + (c & 7)];
        }
        #pragma unroll
        for (int v4 = 0; v4 < 4; ++v4)
            *reinterpret_cast<float4*>(&qtCombF[row][c0 + v4 * 4]) =
                *reinterpret_cast<float4*>(&tmp[v4 * 4]);
    }

    // Q fragments
    s16x8 qf[2];
    {
        int iq = i0 + wave * 16 + l;
        #pragma unroll
        for (int ks = 0; ks < 2; ++ks) {
            uint4 v = make_uint4(0u, 0u, 0u, 0u);
            if (iq < N_)
                v = *reinterpret_cast<const uint4*>(
                    &qkv[(size_t)(b * N_ + iq) * QKV_ + h * D_ + ks * 32 + q * 8]);
            qf[ks] = *reinterpret_cast<s16x8*>(&v);
        }
    }

    float l_part[4] = {0.f, 0.f, 0.f, 0.f};
    f32x4 o_acc[4] = {};

    const int srow = tid >> 3;        // 0..63 (single-issue staging)
    const int g8   = tid & 7;
    const int scol = g8 * 8;
    const int rowq  = wave * 16 + q * 4;  // qtCombF row base
    const int rowq4 = q * 4;              // Ps row base (per wave)

    // prefetch tile 0 (one uint4 each for K and V)
    uint4 kpre, vpre;
    {
        int jg = srow;
        kpre = make_uint4(0u,0u,0u,0u); vpre = make_uint4(0u,0u,0u,0u);
        if (jg < N_) {
            size_t base = (size_t)(b * N_ + jg) * QKV_ + h * D_ + scol;
            kpre = *reinterpret_cast<const uint4*>(&qkv[base + C_]);
            vpre = *reinterpret_cast<const uint4*>(&qkv[base + 2 * C_]);
        }
    }

#define SMAX_BN(bn, MASKED_)                                                  \
    {                                                                         \
        const int jbw = (((bn) << 1) | (l >> 3)) ^ q;                         \
        const int sw = (jbw << 3) | (l & 7);                                  \
        _Pragma("unroll")                                                     \
        for (int r = 0; r < 4; ++r) {                                         \
            int c = (cpk[r] >> ((bn) * 8)) & 63;                              \
            float biasv = qtCombF[rowq + r][c];                               \
            float lg = s[bn][r] + biasv;                                      \
            if (MASKED_) { if ((j0 + (bn) * 16 + l) >= N_) lg = NEGI; }       \
            float p = exp2fast(lg);                                           \
            l_part[r] += p;                                                   \
            Ps[wave][rowq4 + r][sw] = f2bf(p);                                \
        }                                                                     \
    }

#define PVHALF(ks)                                                            \
    {                                                                         \
        const int qi = (l >> 2) & 3;                                          \
        s16x8 pf = *reinterpret_cast<const s16x8*>(                           \
            &Ps[wave][l][((((ks) << 2) | q) ^ qi) << 3]);                     \
        _Pragma("unroll")                                                     \
        for (int bn = 0; bn < 4; ++bn) {                                      \
            int gd = ((bn << 1) | (l >> 3)) & 7;                              \
            int jb = (((ks) << 2) | q) ^ gd;                                  \
            s16x8 vf = *reinterpret_cast<const s16x8*>(&Vt[bn * 16 + l][jb << 3]); \
            o_acc[bn] = __builtin_amdgcn_mfma_f32_16x16x32_bf16(pf, vf, o_acc[bn], 0, 0, 0); \
        }                                                                     \
    }

    const int nJT = (N_ + 63) / 64;   // 17
    for (int jt = 0; jt < nJT; ++jt) {
        const int j0 = jt * 64;

        __syncthreads();   // barrier1: prev compute done; drains prefetch(t)
                           // issued during prev tile's compute (fully covered)

        // commit prefetched K/V; Vt XOR-swizzled
        {
            *reinterpret_cast<uint4*>(&Ks[srow][scol]) = kpre;
            s16x8 v8 = *reinterpret_cast<s16x8*>(&vpre);
            int base = (((srow >> 3) ^ g8) << 3) | (srow & 7);
            #pragma unroll
            for (int e = 0; e < 8; ++e) Vt[scol + e][base] = (u16)v8[e];
        }
        __syncthreads();   // barrier2: lgkm drain only (vmcnt already 0)

        // bucket indices for tile t — issued here, covered by the QK MFMAs
        u32 cpk[4];
        #pragma unroll
        for (int r = 0; r < 4; ++r) {
            int ig = i0 + wave * 16 + q * 4 + r;
            if (ig > CS_ - 1) ig = CS_ - 1;   // pad rows: garbage ok, unstored
            cpk[r] = *reinterpret_cast<const u32*>(&cidx[(size_t)ig * CS_ + j0 + 4 * l]);
        }

        // S = Q K^T, C-initialized to -8*log2e (softmax shift folded in f32)
        f32x4 s[4];
        #pragma unroll
        for (int bn = 0; bn < 4; ++bn)
            s[bn] = (f32x4){-SHIFT2, -SHIFT2, -SHIFT2, -SHIFT2};
        #pragma unroll
        for (int bn = 0; bn < 4; ++bn) {
            #pragma unroll
            for (int ks = 0; ks < 2; ++ks) {
                s16x8 kf = *reinterpret_cast<const s16x8*>(&Ks[bn * 16 + l][ks * 32 + q * 8]);
                s[bn] = __builtin_amdgcn_mfma_f32_16x16x32_bf16(qf[ks], kf, s[bn], 0, 0, 0);
            }
        }

        // prefetch(t+1) — issued here so SMAX+PV covers its latency; kpre/vpre
        // registers are dead after the commit ds_writes above
        {
            int jg = (jt + 1) * 64 + srow;
            kpre = make_uint4(0u,0u,0u,0u); vpre = make_uint4(0u,0u,0u,0u);
            if (jg < N_) {
                size_t base = (size_t)(b * N_ + jg) * QKV_ + h * D_ + scol;
                kpre = *reinterpret_cast<const uint4*>(&qkv[base + C_]);
                vpre = *reinterpret_cast<const uint4*>(&qkv[base + 2 * C_]);
            }
        }

        // softmax halves interleaved with PV halves
        if (jt < nJT - 1) {
            SMAX_BN(0, 0) SMAX_BN(1, 0)
            PVHALF(0)
            SMAX_BN(2, 0) SMAX_BN(3, 0)
            PVHALF(1)
        } else {
            SMAX_BN(0, 1) SMAX_BN(1, 1)
            PVHALF(0)
            SMAX_BN(2, 1) SMAX_BN(3, 1)
            PVHALF(1)
        }
    }

    // epilogue: single l-reduction over the 16-lane row group, then store
    #pragma unroll
    for (int r = 0; r < 4; ++r) {
        #pragma unroll
        for (int s2 = 1; s2 < 16; s2 <<= 1)
            l_part[r] += __shfl_xor(l_part[r], s2, 64);
    }
    #pragma unroll
    for (int bn = 0; bn < 4; ++bn) {
        #pragma unroll
        for (int r = 0; r < 4; ++r) {
            int ig = i0 + wave * 16 + q * 4 + r;
            if (ig < N_) {
                float lsum = l_part[r];
                float invl = (lsum > 0.f) ? (1.0f / lsum) : 0.f;
                aout[(size_t)(b * N_ + ig) * C_ + h * D_ + bn * 16 + l] = f2bf(o_acc[bn][r] * invl);
            }
        }
    }
#undef SMAX_BN
#undef PVHALF
}

extern "C" void kernel_launch(void* const* d_in, const int* in_sizes, int n_in,
                              void* d_out, int out_size, void* d_ws, size_t ws_size,
                              hipStream_t stream)
{
    const float* x      = (const float*)d_in[0];
    const float* qkv_w  = (const float*)d_in[1];
    const float* qkv_b  = (const float*)d_in[2];
    const float* proj_w = (const float*)d_in[3];
    const float* proj_b = (const float*)d_in[4];
    const float* rpe_r  = (const float*)d_in[5];
    const float* rpe_c  = (const float*)d_in[6];
    const int*   brow   = (const int*)d_in[7];
    const int*   bcol   = (const int*)d_in[8];

    // ws layout (56.3MB < proven 67.7MB):
    //   qkv 37.8MB | aout/x_bf16 12.6MB (aliased: x_bf16 consumed by GEMM1
    //   before flash overwrites with aout — stream-ordered) | cidx 1.2MB |
    //   w1_bf16 3.5MB | w2_bf16 1.2MB
    char* p = (char*)d_ws;
    u16* qkv  = (u16*)p; p += (size_t)M_ * QKV_ * 2;
    u16* xaout = (u16*)p; p += (size_t)M_ * C_ * 2;     // x_bf16, then aout
    unsigned char* cidx = (unsigned char*)p; p += (size_t)CS_ * CS_;
    u16* w1bf = (u16*)p; p += (size_t)QKV_ * C_ * 2;
    u16* w2bf = (u16*)p;

    const long nx = (long)M_ * C_;        // 6,297,600
    const long n1 = (long)QKV_ * C_;      // 1,769,472
    const long n2 = (long)C_ * C_;        //   589,824

    // 0a) one-shot bf16 conversion of x / qkv_w / proj_w
    cvt_f32_bf16<<<(int)((nx + n1 + n2) / 8 / 256), 256, 0, stream>>>(
        x, xaout, nx, qkv_w, w1bf, n1, proj_w, w2bf, n2);

    // 0b) packed bucket table
    build_cidx<<<((CS_ * (CS_ / 4)) + 255) / 256, 256, 0, stream>>>(brow, bcol, cidx);

    // 1) qkv = x @ qkv_w^T + qkv_b ; q cols scaled by 0.125*log2e (exp2 fold)
    gemm_bt<0><<<dim3(QKV_ / 128, (M_ + 127) / 128), 256, 0, stream>>>(
        xaout, C_, w1bf, qkv_b, qkv, QKV_, M_, QKV_, C_, C_, 0.125f * LOG2E);

    // 2) MFMA flash attention (8 waves / 128 Q-rows, KVBLK=64)
    flash_kernel<<<dim3((N_ + 127) / 128, B_ * H_), 512, 0, stream>>>(
        qkv, rpe_r, rpe_c, cidx, xaout);

    // 3) out = aout @ proj_w^T + proj_b (bf16 in, fp32 out)
    gemm_bt<1><<<dim3(C_ / 128, (M_ + 127) / 128), 256, 0, stream>>>(
        xaout, C_, w2bf, proj_b, d_out, C_, M_, C_, C_, 0, 1.0f);
}

// Round 12
// 302.248 us; speedup vs baseline: 1.0015x; 1.0015x over previous
//
#include <hip/hip_runtime.h>
#include <hip/hip_bf16.h>

typedef unsigned short u16;
typedef unsigned int   u32;
typedef short  s16x8 __attribute__((ext_vector_type(8)));
typedef float  f32x4 __attribute__((ext_vector_type(4)));

#define B_   8
#define N_   1025
#define H_   12
#define D_   64
#define C_   768
#define NB_  8
#define M_   (B_*N_)     // 8200
#define QKV_ (3*C_)      // 2304
#define NEGI -30000.0f
#define LOG2E 1.44269504089f
#define SHIFT2 11.5415603271f   // 8 * log2(e); softmax shift in exp2 units
#define CS_  1088        // cidx padded rows/stride (17*64)

__device__ __forceinline__ float bf2f(u16 u) {
    unsigned int i = ((unsigned int)u) << 16;
    float f; __builtin_memcpy(&f, &i, 4); return f;
}
// native HW RNE f32->bf16
__device__ __forceinline__ u16 f2bf(float f) {
    __hip_bfloat16 h = __float2bfloat16(f);
    u16 u; __builtin_memcpy(&u, &h, 2); return u;
}
__device__ __forceinline__ float exp2fast(float x) {
#if __has_builtin(__builtin_amdgcn_exp2f)
    return __builtin_amdgcn_exp2f(x);
#else
    float r; asm("v_exp_f32 %0, %1" : "=v"(r) : "v"(x)); return r;
#endif
}

// global -> LDS direct DMA, 16B per lane. lptr must be wave-uniform; HW
// writes lane's 16B at lptr + lane*16. gptr is per-lane.
__device__ __forceinline__ void gload_lds16(const u16* gptr, u16* lptr) {
    __builtin_amdgcn_global_load_lds(
        (const __attribute__((address_space(1))) void*)gptr,
        (__attribute__((address_space(3))) void*)lptr, 16, 0, 0);
}

// ---------------------------------------------------------------------------
// One-shot fp32 -> bf16 (RNE).
// ---------------------------------------------------------------------------
__global__ __launch_bounds__(256)
void cvt_f32_bf16(const float* __restrict__ a, u16* __restrict__ oa, long na,
                  const float* __restrict__ b, u16* __restrict__ ob, long nb,
                  const float* __restrict__ c, u16* __restrict__ oc, long nc)
{
    long t = ((long)blockIdx.x * 256 + threadIdx.x) * 8;
    const float* s; u16* d; long off;
    if (t < na)                 { s = a; d = oa; off = t; }
    else if (t < na + nb)       { s = b; d = ob; off = t - na; }
    else if (t < na + nb + nc)  { s = c; d = oc; off = t - na - nb; }
    else return;
    float4 f0 = *reinterpret_cast<const float4*>(s + off);
    float4 f1 = *reinterpret_cast<const float4*>(s + off + 4);
    u16 tmp[8] = { f2bf(f0.x), f2bf(f0.y), f2bf(f0.z), f2bf(f0.w),
                   f2bf(f1.x), f2bf(f1.y), f2bf(f1.z), f2bf(f1.w) };
    *reinterpret_cast<uint4*>(d + off) = *reinterpret_cast<uint4*>(tmp);
}

// Packed+permuted bucket table: byte at [i][jt*64 + 4*l + bn] = brow*8+bcol for
// j = jt*64 + bn*16 + l.
__global__ void build_cidx(const int* __restrict__ brow, const int* __restrict__ bcol,
                           unsigned char* __restrict__ cidx) {
    long t = (long)blockIdx.x * 256 + threadIdx.x;
    const long total = (long)CS_ * (CS_ / 4);
    if (t >= total) return;
    int i = (int)(t / (CS_ / 4));
    int k = (int)(t % (CS_ / 4));
    u32 w = 0;
    int p0 = k * 4;
    #pragma unroll
    for (int bnb = 0; bnb < 4; ++bnb) {
        int p = p0 + bnb;
        int jt = p >> 6, rem = p & 63;
        int l = rem >> 2, bn = rem & 3;
        int j = jt * 64 + bn * 16 + l;
        u32 c = 63u;
        if (i < N_ && j < N_) {
            u32 br = (u32)(brow[(size_t)i * N_ + j] & 7);
            u32 bc = (u32)(bcol[(size_t)i * N_ + j] & 7);
            c = (br << 3) | bc;
        }
        w |= c << (8 * bnb);
    }
    ((u32*)cidx)[t] = w;
}

// ---------------------------------------------------------------------------
// GEMM: Cout[M,Nn](ldc) = A[M,K](lda) @ Bt[Nn,K]^T + bias. bf16 operands.
// BK=64, LDS [128][64] staged via global_load_lds with pre-swizzled global
// source columns; swizzled fragment reads (2-way max bank aliasing).
// (Proven R10 kernel, unchanged.)
// ---------------------------------------------------------------------------
template<int OF32>
__global__ __launch_bounds__(256)
void gemm_bt(const u16* __restrict__ Ap, int lda,
             const u16* __restrict__ Btp,
             const float* __restrict__ bias,
             void* __restrict__ Cout, int ldc,
             int M, int Nn, int K, int scale_cols, float scale_val)
{
    __shared__ u16 As[128][64];
    __shared__ u16 Bs[128][64];
    const int tid  = threadIdx.x;
    const int lane = tid & 63;
    const int wave = tid >> 6;
    const int wm = (wave >> 1) * 64;
    const int wn = (wave & 1) * 64;
    const int m0 = blockIdx.y * 128;
    const int n0 = blockIdx.x * 128;

    const int srow = wave * 32 + (lane >> 3);
    const int gcol = (((lane & 7) ^ ((lane >> 3) & 7))) * 8;   // pre-swizzled

    f32x4 acc[4][4] = {};

    for (int k0 = 0; k0 < K; k0 += 64) {
        __syncthreads();
        #pragma unroll
        for (int i = 0; i < 4; ++i) {
            int ar = m0 + srow + i * 8;
            if (ar > M - 1) ar = M - 1;                    // clamp (valid addr)
            gload_lds16(Ap + (size_t)ar * lda + k0 + gcol, &As[wave * 32 + i * 8][0]);
            int br = n0 + srow + i * 8;                    // Nn % 128 == 0
            gload_lds16(Btp + (size_t)br * K + k0 + gcol,  &Bs[wave * 32 + i * 8][0]);
        }
        __syncthreads();

        #pragma unroll
        for (int kk = 0; kk < 2; ++kk) {
            const int kc = ((kk * 4 + (lane >> 4)) ^ (lane & 7)) << 3;  // swizzled read col
            s16x8 af[4], bfv[4];
            #pragma unroll
            for (int qq = 0; qq < 4; ++qq) {
                af[qq]  = *reinterpret_cast<const s16x8*>(&As[wm + qq*16 + (lane & 15)][kc]);
                bfv[qq] = *reinterpret_cast<const s16x8*>(&Bs[wn + qq*16 + (lane & 15)][kc]);
            }
            #pragma unroll
            for (int bm = 0; bm < 4; ++bm)
                #pragma unroll
                for (int bn = 0; bn < 4; ++bn)
                    acc[bm][bn] = __builtin_amdgcn_mfma_f32_16x16x32_bf16(af[bm], bfv[bn], acc[bm][bn], 0, 0, 0);
        }
    }

    #pragma unroll
    for (int bm = 0; bm < 4; ++bm) {
        #pragma unroll
        for (int bn = 0; bn < 4; ++bn) {
            int col = n0 + wn + bn*16 + (lane & 15);
            float bv = bias[col];
            float sc = (col < scale_cols) ? scale_val : 1.0f;
            #pragma unroll
            for (int r = 0; r < 4; ++r) {
                int row = m0 + wm + bm*16 + (lane >> 4)*4 + r;
                if (row < M) {
                    float v = (acc[bm][bn][r] + bv) * sc;
                    size_t idx = (size_t)row * ldc + col;
                    if (OF32) ((float*)Cout)[idx] = v;
                    else      ((u16*)Cout)[idx]   = f2bf(v);
                }
            }
        }
    }
}

// ---------------------------------------------------------------------------
// MFMA flash attention — R10 structure + (a) wave-activity gate: the tail
// block (i0=1024) has 1 valid Q-row; waves with no valid rows skip
// cpk/QK/SMAX/PV (staging + barriers stay block-wide), cutting ~11% of grid
// compute; (b) s_setprio(1) around the QK and PV MFMA clusters (T5, isolated
// — 2 desynced blocks/CU = m191's positive regime); (c) qtCombF [128][68]
// pad (R11: bank conflicts -33%). Load placement = R10 (R11's reorder
// stretched kpre/vpre live ranges into spill — reverted).
// __launch_bounds__(512,4): 2 blocks/CU (R8: residency > spill).
// ---------------------------------------------------------------------------
__global__ __launch_bounds__(512, 4)
void flash_kernel(const u16* __restrict__ qkv,
                  const float* __restrict__ rpe_r, const float* __restrict__ rpe_c,
                  const unsigned char* __restrict__ cidx,
                  u16* __restrict__ aout)
{
    __shared__ u16 Ks[64][72];       // [j][d]                       9216 B
    __shared__ u16 Vt[64][72];       // [d][swz(j)]                  9216 B
    __shared__ u16 Ps[8][16][72];    // [wave][i][swz(j)]           18432 B
    __shared__ float qtCombF[128][68]; // [row][u*8+v] f32, +4 pad  34816 B
    // total 71680 B/block -> 2 blocks/CU

    const int tid  = threadIdx.x;
    const int lane = tid & 63;
    const int wave = tid >> 6;       // 0..7
    const int q    = lane >> 4;      // 0..3
    const int l    = lane & 15;
    const int bh = blockIdx.y;
    const int b = bh / H_;
    const int h = bh % H_;
    const int i0 = blockIdx.x * 128;
    const bool wactive = (i0 + wave * 16) < N_;   // wave has >=1 valid Q-row

    float* qtrA = (float*)&Ps[0][0][0];   // [128][8] (aliased, prologue only)
    float* qtcA = qtrA + 128 * 8;         // [128][8]

    // ---- phase A: per-row qt projections (row=t>>2, u={2*(t&3),+1}), streaming
    {
        int row = tid >> 2;              // 0..127
        int u0  = (tid & 3) * 2;
        int ig = i0 + row;
        bool valid = ig < N_;
        const u16* qrow = &qkv[(size_t)(b * N_ + (valid ? ig : 0)) * QKV_ + h * D_];
        #pragma unroll
        for (int uu = 0; uu < 2; ++uu) {
            int u = u0 + uu;
            const float4* rr4 = (const float4*)&rpe_r[(size_t)(h * NB_ + u) * D_];
            const float4* rc4 = (const float4*)&rpe_c[(size_t)(h * NB_ + u) * D_];
            float sr = 0.f, sc = 0.f;
            #pragma unroll
            for (int e2 = 0; e2 < 8; ++e2) {
                uint4 t = *reinterpret_cast<const uint4*>(&qrow[e2 * 8]);
                s16x8 q8 = *reinterpret_cast<s16x8*>(&t);
                float4 a0 = rr4[2*e2], a1 = rr4[2*e2+1];
                float4 c0 = rc4[2*e2], c1 = rc4[2*e2+1];
                float f0 = bf2f((u16)q8[0]), f1 = bf2f((u16)q8[1]);
                float f2 = bf2f((u16)q8[2]), f3 = bf2f((u16)q8[3]);
                float f4 = bf2f((u16)q8[4]), f5 = bf2f((u16)q8[5]);
                float f6 = bf2f((u16)q8[6]), f7 = bf2f((u16)q8[7]);
                sr += f0*a0.x + f1*a0.y + f2*a0.z + f3*a0.w
                    + f4*a1.x + f5*a1.y + f6*a1.z + f7*a1.w;
                sc += f0*c0.x + f1*c0.y + f2*c0.z + f3*c0.w
                    + f4*c1.x + f5*c1.y + f6*c1.z + f7*c1.w;
            }
            qtrA[row*8 + u] = valid ? sr : 0.f;
            qtcA[row*8 + u] = valid ? sc : 0.f;
        }
    }
    __syncthreads();
    // ---- phase B: qtCombF[row][u*8+v] = qtr[u]+qtc[v] (f32)
    {
        int row = tid >> 2;
        int c0  = (tid & 3) * 16;
        float tmp[16];
        #pragma unroll
        for (int cc = 0; cc < 16; ++cc) {
            int c = c0 + cc;
            tmp[cc] = qtrA[row*8 + (c >> 3)] + qtcA[row*8 + (c & 7)];
        }
        #pragma unroll
        for (int v4 = 0; v4 < 4; ++v4)
            *reinterpret_cast<float4*>(&qtCombF[row][c0 + v4 * 4]) =
                *reinterpret_cast<float4*>(&tmp[v4 * 4]);
    }

    // Q fragments
    s16x8 qf[2];
    {
        int iq = i0 + wave * 16 + l;
        #pragma unroll
        for (int ks = 0; ks < 2; ++ks) {
            uint4 v = make_uint4(0u, 0u, 0u, 0u);
            if (iq < N_)
                v = *reinterpret_cast<const uint4*>(
                    &qkv[(size_t)(b * N_ + iq) * QKV_ + h * D_ + ks * 32 + q * 8]);
            qf[ks] = *reinterpret_cast<s16x8*>(&v);
        }
    }

    float l_part[4] = {0.f, 0.f, 0.f, 0.f};
    f32x4 o_acc[4] = {};

    const int srow = tid >> 3;        // 0..63 (single-issue staging)
    const int g8   = tid & 7;
    const int scol = g8 * 8;
    const int rowq  = wave * 16 + q * 4;  // qtCombF row base
    const int rowq4 = q * 4;              // Ps row base (per wave)

    // prefetch tile 0 (one uint4 each for K and V)
    uint4 kpre, vpre;
    {
        int jg = srow;
        kpre = make_uint4(0u,0u,0u,0u); vpre = make_uint4(0u,0u,0u,0u);
        if (jg < N_) {
            size_t base = (size_t)(b * N_ + jg) * QKV_ + h * D_ + scol;
            kpre = *reinterpret_cast<const uint4*>(&qkv[base + C_]);
            vpre = *reinterpret_cast<const uint4*>(&qkv[base + 2 * C_]);
        }
    }

#define SMAX_BN(bn, MASKED_)                                                  \
    {                                                                         \
        const int jbw = (((bn) << 1) | (l >> 3)) ^ q;                         \
        const int sw = (jbw << 3) | (l & 7);                                  \
        _Pragma("unroll")                                                     \
        for (int r = 0; r < 4; ++r) {                                         \
            int c = (cpk[r] >> ((bn) * 8)) & 63;                              \
            float biasv = qtCombF[rowq + r][c];                               \
            float lg = s[bn][r] + biasv;                                      \
            if (MASKED_) { if ((j0 + (bn) * 16 + l) >= N_) lg = NEGI; }       \
            float p = exp2fast(lg);                                           \
            l_part[r] += p;                                                   \
            Ps[wave][rowq4 + r][sw] = f2bf(p);                                \
        }                                                                     \
    }

#define PVHALF(ks)                                                            \
    {                                                                         \
        const int qi = (l >> 2) & 3;                                          \
        s16x8 pf = *reinterpret_cast<const s16x8*>(                           \
            &Ps[wave][l][((((ks) << 2) | q) ^ qi) << 3]);                     \
        __builtin_amdgcn_s_setprio(1);                                        \
        _Pragma("unroll")                                                     \
        for (int bn = 0; bn < 4; ++bn) {                                      \
            int gd = ((bn << 1) | (l >> 3)) & 7;                              \
            int jb = (((ks) << 2) | q) ^ gd;                                  \
            s16x8 vf = *reinterpret_cast<const s16x8*>(&Vt[bn * 16 + l][jb << 3]); \
            o_acc[bn] = __builtin_amdgcn_mfma_f32_16x16x32_bf16(pf, vf, o_acc[bn], 0, 0, 0); \
        }                                                                     \
        __builtin_amdgcn_s_setprio(0);                                        \
    }

    const int nJT = (N_ + 63) / 64;   // 17
    for (int jt = 0; jt < nJT; ++jt) {
        const int j0 = jt * 64;

        // packed bucket indices — hoisted above the barrier (R10 placement)
        u32 cpk[4];
        if (wactive) {
            #pragma unroll
            for (int r = 0; r < 4; ++r) {
                int ig = i0 + wave * 16 + q * 4 + r;
                if (ig > CS_ - 1) ig = CS_ - 1;   // pad rows: garbage ok, unstored
                cpk[r] = *reinterpret_cast<const u32*>(&cidx[(size_t)ig * CS_ + j0 + 4 * l]);
            }
        }

        __syncthreads();

        // commit prefetched K/V; Vt XOR-swizzled (block-wide)
        {
            *reinterpret_cast<uint4*>(&Ks[srow][scol]) = kpre;
            s16x8 v8 = *reinterpret_cast<s16x8*>(&vpre);
            int base = (((srow >> 3) ^ g8) << 3) | (srow & 7);
            #pragma unroll
            for (int e = 0; e < 8; ++e) Vt[scol + e][base] = (u16)v8[e];
        }
        // prefetch next tile (block-wide; R10 placement)
        {
            int jg = (jt + 1) * 64 + srow;
            kpre = make_uint4(0u,0u,0u,0u); vpre = make_uint4(0u,0u,0u,0u);
            if (jg < N_) {
                size_t base = (size_t)(b * N_ + jg) * QKV_ + h * D_ + scol;
                kpre = *reinterpret_cast<const uint4*>(&qkv[base + C_]);
                vpre = *reinterpret_cast<const uint4*>(&qkv[base + 2 * C_]);
            }
        }
        __syncthreads();

        if (wactive) {
            // S = Q K^T, C-initialized to -8*log2e
            f32x4 s[4];
            #pragma unroll
            for (int bn = 0; bn < 4; ++bn)
                s[bn] = (f32x4){-SHIFT2, -SHIFT2, -SHIFT2, -SHIFT2};
            __builtin_amdgcn_s_setprio(1);
            #pragma unroll
            for (int bn = 0; bn < 4; ++bn) {
                #pragma unroll
                for (int ks = 0; ks < 2; ++ks) {
                    s16x8 kf = *reinterpret_cast<const s16x8*>(&Ks[bn * 16 + l][ks * 32 + q * 8]);
                    s[bn] = __builtin_amdgcn_mfma_f32_16x16x32_bf16(qf[ks], kf, s[bn], 0, 0, 0);
                }
            }
            __builtin_amdgcn_s_setprio(0);

            // softmax halves interleaved with PV halves
            if (jt < nJT - 1) {
                SMAX_BN(0, 0) SMAX_BN(1, 0)
                PVHALF(0)
                SMAX_BN(2, 0) SMAX_BN(3, 0)
                PVHALF(1)
            } else {
                SMAX_BN(0, 1) SMAX_BN(1, 1)
                PVHALF(0)
                SMAX_BN(2, 1) SMAX_BN(3, 1)
                PVHALF(1)
            }
        }
    }

    // epilogue: single l-reduction over the 16-lane row group, then store
    #pragma unroll
    for (int r = 0; r < 4; ++r) {
        #pragma unroll
        for (int s2 = 1; s2 < 16; s2 <<= 1)
            l_part[r] += __shfl_xor(l_part[r], s2, 64);
    }
    #pragma unroll
    for (int bn = 0; bn < 4; ++bn) {
        #pragma unroll
        for (int r = 0; r < 4; ++r) {
            int ig = i0 + wave * 16 + q * 4 + r;
            if (ig < N_) {
                float lsum = l_part[r];
                float invl = (lsum > 0.f) ? (1.0f / lsum) : 0.f;
                aout[(size_t)(b * N_ + ig) * C_ + h * D_ + bn * 16 + l] = f2bf(o_acc[bn][r] * invl);
            }
        }
    }
#undef SMAX_BN
#undef PVHALF
}

extern "C" void kernel_launch(void* const* d_in, const int* in_sizes, int n_in,
                              void* d_out, int out_size, void* d_ws, size_t ws_size,
                              hipStream_t stream)
{
    const float* x      = (const float*)d_in[0];
    const float* qkv_w  = (const float*)d_in[1];
    const float* qkv_b  = (const float*)d_in[2];
    const float* proj_w = (const float*)d_in[3];
    const float* proj_b = (const float*)d_in[4];
    const float* rpe_r  = (const float*)d_in[5];
    const float* rpe_c  = (const float*)d_in[6];
    const int*   brow   = (const int*)d_in[7];
    const int*   bcol   = (const int*)d_in[8];

    // ws layout (56.3MB < proven 67.7MB):
    //   qkv 37.8MB | aout/x_bf16 12.6MB (aliased: x_bf16 consumed by GEMM1
    //   before flash overwrites with aout — stream-ordered) | cidx 1.2MB |
    //   w1_bf16 3.5MB | w2_bf16 1.2MB
    char* p = (char*)d_ws;
    u16* qkv  = (u16*)p; p += (size_t)M_ * QKV_ * 2;
    u16* xaout = (u16*)p; p += (size_t)M_ * C_ * 2;     // x_bf16, then aout
    unsigned char* cidx = (unsigned char*)p; p += (size_t)CS_ * CS_;
    u16* w1bf = (u16*)p; p += (size_t)QKV_ * C_ * 2;
    u16* w2bf = (u16*)p;

    const long nx = (long)M_ * C_;        // 6,297,600
    const long n1 = (long)QKV_ * C_;      // 1,769,472
    const long n2 = (long)C_ * C_;        //   589,824

    // 0a) one-shot bf16 conversion of x / qkv_w / proj_w
    cvt_f32_bf16<<<(int)((nx + n1 + n2) / 8 / 256), 256, 0, stream>>>(
        x, xaout, nx, qkv_w, w1bf, n1, proj_w, w2bf, n2);

    // 0b) packed bucket table
    build_cidx<<<((CS_ * (CS_ / 4)) + 255) / 256, 256, 0, stream>>>(brow, bcol, cidx);

    // 1) qkv = x @ qkv_w^T + qkv_b ; q cols scaled by 0.125*log2e (exp2 fold)
    gemm_bt<0><<<dim3(QKV_ / 128, (M_ + 127) / 128), 256, 0, stream>>>(
        xaout, C_, w1bf, qkv_b, qkv, QKV_, M_, QKV_, C_, C_, 0.125f * LOG2E);

    // 2) MFMA flash attention (8 waves / 128 Q-rows, KVBLK=64)
    flash_kernel<<<dim3((N_ + 127) / 128, B_ * H_), 512, 0, stream>>>(
        qkv, rpe_r, rpe_c, cidx, xaout);

    // 3) out = aout @ proj_w^T + proj_b (bf16 in, fp32 out)
    gemm_bt<1><<<dim3(C_ / 128, (M_ + 127) / 128), 256, 0, stream>>>(
        xaout, C_, w2bf, proj_b, d_out, C_, M_, C_, C_, 0, 1.0f);
}

// Round 13
// 294.700 us; speedup vs baseline: 1.0272x; 1.0256x over previous
//
#include <hip/hip_runtime.h>
#include <hip/hip_bf16.h>

typedef unsigned short u16;
typedef unsigned int   u32;
typedef short  s16x8 __attribute__((ext_vector_type(8)));
typedef float  f32x4 __attribute__((ext_vector_type(4)));

#define B_   8
#define N_   1025
#define H_   12
#define D_   64
#define C_   768
#define NB_  8
#define M_   (B_*N_)     // 8200
#define QKV_ (3*C_)      // 2304
#define NEGI -30000.0f
#define LOG2E 1.44269504089f
#define SHIFT2 11.5415603271f   // 8 * log2(e); softmax shift in exp2 units
#define CS_  1088        // cidx padded rows/stride (17*64)

__device__ __forceinline__ float bf2f(u16 u) {
    unsigned int i = ((unsigned int)u) << 16;
    float f; __builtin_memcpy(&f, &i, 4); return f;
}
// native HW RNE f32->bf16
__device__ __forceinline__ u16 f2bf(float f) {
    __hip_bfloat16 h = __float2bfloat16(f);
    u16 u; __builtin_memcpy(&u, &h, 2); return u;
}
__device__ __forceinline__ float exp2fast(float x) {
#if __has_builtin(__builtin_amdgcn_exp2f)
    return __builtin_amdgcn_exp2f(x);
#else
    float r; asm("v_exp_f32 %0, %1" : "=v"(r) : "v"(x)); return r;
#endif
}

// global -> LDS direct DMA, 16B per lane. lptr must be wave-uniform; HW
// writes lane's 16B at lptr + lane*16. gptr is per-lane.
__device__ __forceinline__ void gload_lds16(const u16* gptr, u16* lptr) {
    __builtin_amdgcn_global_load_lds(
        (const __attribute__((address_space(1))) void*)gptr,
        (__attribute__((address_space(3))) void*)lptr, 16, 0, 0);
}

// ---------------------------------------------------------------------------
// One-shot fp32 -> bf16 (RNE).
// ---------------------------------------------------------------------------
__global__ __launch_bounds__(256)
void cvt_f32_bf16(const float* __restrict__ a, u16* __restrict__ oa, long na,
                  const float* __restrict__ b, u16* __restrict__ ob, long nb,
                  const float* __restrict__ c, u16* __restrict__ oc, long nc)
{
    long t = ((long)blockIdx.x * 256 + threadIdx.x) * 8;
    const float* s; u16* d; long off;
    if (t < na)                 { s = a; d = oa; off = t; }
    else if (t < na + nb)       { s = b; d = ob; off = t - na; }
    else if (t < na + nb + nc)  { s = c; d = oc; off = t - na - nb; }
    else return;
    float4 f0 = *reinterpret_cast<const float4*>(s + off);
    float4 f1 = *reinterpret_cast<const float4*>(s + off + 4);
    u16 tmp[8] = { f2bf(f0.x), f2bf(f0.y), f2bf(f0.z), f2bf(f0.w),
                   f2bf(f1.x), f2bf(f1.y), f2bf(f1.z), f2bf(f1.w) };
    *reinterpret_cast<uint4*>(d + off) = *reinterpret_cast<uint4*>(tmp);
}

// Packed+permuted bucket table: byte at [i][jt*64 + 4*l + bn] = brow*8+bcol for
// j = jt*64 + bn*16 + l.
__global__ void build_cidx(const int* __restrict__ brow, const int* __restrict__ bcol,
                           unsigned char* __restrict__ cidx) {
    long t = (long)blockIdx.x * 256 + threadIdx.x;
    const long total = (long)CS_ * (CS_ / 4);
    if (t >= total) return;
    int i = (int)(t / (CS_ / 4));
    int k = (int)(t % (CS_ / 4));
    u32 w = 0;
    int p0 = k * 4;
    #pragma unroll
    for (int bnb = 0; bnb < 4; ++bnb) {
        int p = p0 + bnb;
        int jt = p >> 6, rem = p & 63;
        int l = rem >> 2, bn = rem & 3;
        int j = jt * 64 + bn * 16 + l;
        u32 c = 63u;
        if (i < N_ && j < N_) {
            u32 br = (u32)(brow[(size_t)i * N_ + j] & 7);
            u32 bc = (u32)(bcol[(size_t)i * N_ + j] & 7);
            c = (br << 3) | bc;
        }
        w |= c << (8 * bnb);
    }
    ((u32*)cidx)[t] = w;
}

// ---------------------------------------------------------------------------
// GEMM: Cout[M,Nn](ldc) = A[M,K](lda) @ Bt[Nn,K]^T + bias. bf16 operands.
// BK=64, LDS [128][64] staged via global_load_lds with pre-swizzled global
// source columns; swizzled fragment reads (2-way max bank aliasing).
// (Proven R10 kernel, unchanged.)
// ---------------------------------------------------------------------------
template<int OF32>
__global__ __launch_bounds__(256)
void gemm_bt(const u16* __restrict__ Ap, int lda,
             const u16* __restrict__ Btp,
             const float* __restrict__ bias,
             void* __restrict__ Cout, int ldc,
             int M, int Nn, int K, int scale_cols, float scale_val)
{
    __shared__ u16 As[128][64];
    __shared__ u16 Bs[128][64];
    const int tid  = threadIdx.x;
    const int lane = tid & 63;
    const int wave = tid >> 6;
    const int wm = (wave >> 1) * 64;
    const int wn = (wave & 1) * 64;
    const int m0 = blockIdx.y * 128;
    const int n0 = blockIdx.x * 128;

    const int srow = wave * 32 + (lane >> 3);
    const int gcol = (((lane & 7) ^ ((lane >> 3) & 7))) * 8;   // pre-swizzled

    f32x4 acc[4][4] = {};

    for (int k0 = 0; k0 < K; k0 += 64) {
        __syncthreads();
        #pragma unroll
        for (int i = 0; i < 4; ++i) {
            int ar = m0 + srow + i * 8;
            if (ar > M - 1) ar = M - 1;                    // clamp (valid addr)
            gload_lds16(Ap + (size_t)ar * lda + k0 + gcol, &As[wave * 32 + i * 8][0]);
            int br = n0 + srow + i * 8;                    // Nn % 128 == 0
            gload_lds16(Btp + (size_t)br * K + k0 + gcol,  &Bs[wave * 32 + i * 8][0]);
        }
        __syncthreads();

        #pragma unroll
        for (int kk = 0; kk < 2; ++kk) {
            const int kc = ((kk * 4 + (lane >> 4)) ^ (lane & 7)) << 3;  // swizzled read col
            s16x8 af[4], bfv[4];
            #pragma unroll
            for (int qq = 0; qq < 4; ++qq) {
                af[qq]  = *reinterpret_cast<const s16x8*>(&As[wm + qq*16 + (lane & 15)][kc]);
                bfv[qq] = *reinterpret_cast<const s16x8*>(&Bs[wn + qq*16 + (lane & 15)][kc]);
            }
            #pragma unroll
            for (int bm = 0; bm < 4; ++bm)
                #pragma unroll
                for (int bn = 0; bn < 4; ++bn)
                    acc[bm][bn] = __builtin_amdgcn_mfma_f32_16x16x32_bf16(af[bm], bfv[bn], acc[bm][bn], 0, 0, 0);
        }
    }

    #pragma unroll
    for (int bm = 0; bm < 4; ++bm) {
        #pragma unroll
        for (int bn = 0; bn < 4; ++bn) {
            int col = n0 + wn + bn*16 + (lane & 15);
            float bv = bias[col];
            float sc = (col < scale_cols) ? scale_val : 1.0f;
            #pragma unroll
            for (int r = 0; r < 4; ++r) {
                int row = m0 + wm + bm*16 + (lane >> 4)*4 + r;
                if (row < M) {
                    float v = (acc[bm][bn][r] + bv) * sc;
                    size_t idx = (size_t)row * ldc + col;
                    if (OF32) ((float*)Cout)[idx] = v;
                    else      ((u16*)Cout)[idx]   = f2bf(v);
                }
            }
        }
    }
}

// ---------------------------------------------------------------------------
// MFMA flash attention — R12 structure + XCD-grouped block mapping (T1):
// 1-D grid of 864 blocks; linear id L -> xcd=L&7, s=L>>3, bh=xcd+8*(s/9),
// bx=s%9 (bijective: 864=8*12*9). All 9 i-blocks of a (b,h) get ids
// congruent mod 8 -> same XCD -> its 256KB K/V panel is fetched from HBM
// once and L2-served to the other 8 blocks (HBM-miss ~900cyc vs L2 ~200cyc;
// the 1-tile prefetch covers L2 latency but not HBM).
// Retained from R12: tail-wave gate, setprio on MFMA clusters, qtCombF
// [128][68] pad, R10 load placement, __launch_bounds__(512,4).
// ---------------------------------------------------------------------------
__global__ __launch_bounds__(512, 4)
void flash_kernel(const u16* __restrict__ qkv,
                  const float* __restrict__ rpe_r, const float* __restrict__ rpe_c,
                  const unsigned char* __restrict__ cidx,
                  u16* __restrict__ aout)
{
    __shared__ u16 Ks[64][72];       // [j][d]                       9216 B
    __shared__ u16 Vt[64][72];       // [d][swz(j)]                  9216 B
    __shared__ u16 Ps[8][16][72];    // [wave][i][swz(j)]           18432 B
    __shared__ float qtCombF[128][68]; // [row][u*8+v] f32, +4 pad  34816 B
    // total 71680 B/block -> 2 blocks/CU

    const int tid  = threadIdx.x;
    const int lane = tid & 63;
    const int wave = tid >> 6;       // 0..7
    const int q    = lane >> 4;      // 0..3
    const int l    = lane & 15;

    // XCD-grouped mapping (bijective, 864 = 8 xcds * 12 bh-groups * 9 blocks)
    const int L   = blockIdx.x;
    const int xcd = L & 7;
    const int s_  = L >> 3;              // 0..107
    const int bh  = xcd + 8 * (s_ / 9);  // 0..95
    const int bx  = s_ % 9;              // 0..8
    const int b = bh / H_;
    const int h = bh % H_;
    const int i0 = bx * 128;
    const bool wactive = (i0 + wave * 16) < N_;   // wave has >=1 valid Q-row

    float* qtrA = (float*)&Ps[0][0][0];   // [128][8] (aliased, prologue only)
    float* qtcA = qtrA + 128 * 8;         // [128][8]

    // ---- phase A: per-row qt projections (row=t>>2, u={2*(t&3),+1}), streaming
    {
        int row = tid >> 2;              // 0..127
        int u0  = (tid & 3) * 2;
        int ig = i0 + row;
        bool valid = ig < N_;
        const u16* qrow = &qkv[(size_t)(b * N_ + (valid ? ig : 0)) * QKV_ + h * D_];
        #pragma unroll
        for (int uu = 0; uu < 2; ++uu) {
            int u = u0 + uu;
            const float4* rr4 = (const float4*)&rpe_r[(size_t)(h * NB_ + u) * D_];
            const float4* rc4 = (const float4*)&rpe_c[(size_t)(h * NB_ + u) * D_];
            float sr = 0.f, sc = 0.f;
            #pragma unroll
            for (int e2 = 0; e2 < 8; ++e2) {
                uint4 t = *reinterpret_cast<const uint4*>(&qrow[e2 * 8]);
                s16x8 q8 = *reinterpret_cast<s16x8*>(&t);
                float4 a0 = rr4[2*e2], a1 = rr4[2*e2+1];
                float4 c0 = rc4[2*e2], c1 = rc4[2*e2+1];
                float f0 = bf2f((u16)q8[0]), f1 = bf2f((u16)q8[1]);
                float f2 = bf2f((u16)q8[2]), f3 = bf2f((u16)q8[3]);
                float f4 = bf2f((u16)q8[4]), f5 = bf2f((u16)q8[5]);
                float f6 = bf2f((u16)q8[6]), f7 = bf2f((u16)q8[7]);
                sr += f0*a0.x + f1*a0.y + f2*a0.z + f3*a0.w
                    + f4*a1.x + f5*a1.y + f6*a1.z + f7*a1.w;
                sc += f0*c0.x + f1*c0.y + f2*c0.z + f3*c0.w
                    + f4*c1.x + f5*c1.y + f6*c1.z + f7*c1.w;
            }
            qtrA[row*8 + u] = valid ? sr : 0.f;
            qtcA[row*8 + u] = valid ? sc : 0.f;
        }
    }
    __syncthreads();
    // ---- phase B: qtCombF[row][u*8+v] = qtr[u]+qtc[v] (f32)
    {
        int row = tid >> 2;
        int c0  = (tid & 3) * 16;
        float tmp[16];
        #pragma unroll
        for (int cc = 0; cc < 16; ++cc) {
            int c = c0 + cc;
            tmp[cc] = qtrA[row*8 + (c >> 3)] + qtcA[row*8 + (c & 7)];
        }
        #pragma unroll
        for (int v4 = 0; v4 < 4; ++v4)
            *reinterpret_cast<float4*>(&qtCombF[row][c0 + v4 * 4]) =
                *reinterpret_cast<float4*>(&tmp[v4 * 4]);
    }

    // Q fragments
    s16x8 qf[2];
    {
        int iq = i0 + wave * 16 + l;
        #pragma unroll
        for (int ks = 0; ks < 2; ++ks) {
            uint4 v = make_uint4(0u, 0u, 0u, 0u);
            if (iq < N_)
                v = *reinterpret_cast<const uint4*>(
                    &qkv[(size_t)(b * N_ + iq) * QKV_ + h * D_ + ks * 32 + q * 8]);
            qf[ks] = *reinterpret_cast<s16x8*>(&v);
        }
    }

    float l_part[4] = {0.f, 0.f, 0.f, 0.f};
    f32x4 o_acc[4] = {};

    const int srow = tid >> 3;        // 0..63 (single-issue staging)
    const int g8   = tid & 7;
    const int scol = g8 * 8;
    const int rowq  = wave * 16 + q * 4;  // qtCombF row base
    const int rowq4 = q * 4;              // Ps row base (per wave)

    // prefetch tile 0 (one uint4 each for K and V)
    uint4 kpre, vpre;
    {
        int jg = srow;
        kpre = make_uint4(0u,0u,0u,0u); vpre = make_uint4(0u,0u,0u,0u);
        if (jg < N_) {
            size_t base = (size_t)(b * N_ + jg) * QKV_ + h * D_ + scol;
            kpre = *reinterpret_cast<const uint4*>(&qkv[base + C_]);
            vpre = *reinterpret_cast<const uint4*>(&qkv[base + 2 * C_]);
        }
    }

#define SMAX_BN(bn, MASKED_)                                                  \
    {                                                                         \
        const int jbw = (((bn) << 1) | (l >> 3)) ^ q;                         \
        const int sw = (jbw << 3) | (l & 7);                                  \
        _Pragma("unroll")                                                     \
        for (int r = 0; r < 4; ++r) {                                         \
            int c = (cpk[r] >> ((bn) * 8)) & 63;                              \
            float biasv = qtCombF[rowq + r][c];                               \
            float lg = s[bn][r] + biasv;                                      \
            if (MASKED_) { if ((j0 + (bn) * 16 + l) >= N_) lg = NEGI; }       \
            float p = exp2fast(lg);                                           \
            l_part[r] += p;                                                   \
            Ps[wave][rowq4 + r][sw] = f2bf(p);                                \
        }                                                                     \
    }

#define PVHALF(ks)                                                            \
    {                                                                         \
        const int qi = (l >> 2) & 3;                                          \
        s16x8 pf = *reinterpret_cast<const s16x8*>(                           \
            &Ps[wave][l][((((ks) << 2) | q) ^ qi) << 3]);                     \
        __builtin_amdgcn_s_setprio(1);                                        \
        _Pragma("unroll")                                                     \
        for (int bn = 0; bn < 4; ++bn) {                                      \
            int gd = ((bn << 1) | (l >> 3)) & 7;                              \
            int jb = (((ks) << 2) | q) ^ gd;                                  \
            s16x8 vf = *reinterpret_cast<const s16x8*>(&Vt[bn * 16 + l][jb << 3]); \
            o_acc[bn] = __builtin_amdgcn_mfma_f32_16x16x32_bf16(pf, vf, o_acc[bn], 0, 0, 0); \
        }                                                                     \
        __builtin_amdgcn_s_setprio(0);                                        \
    }

    const int nJT = (N_ + 63) / 64;   // 17
    for (int jt = 0; jt < nJT; ++jt) {
        const int j0 = jt * 64;

        // packed bucket indices — hoisted above the barrier (R10 placement)
        u32 cpk[4];
        if (wactive) {
            #pragma unroll
            for (int r = 0; r < 4; ++r) {
                int ig = i0 + wave * 16 + q * 4 + r;
                if (ig > CS_ - 1) ig = CS_ - 1;   // pad rows: garbage ok, unstored
                cpk[r] = *reinterpret_cast<const u32*>(&cidx[(size_t)ig * CS_ + j0 + 4 * l]);
            }
        }

        __syncthreads();

        // commit prefetched K/V; Vt XOR-swizzled (block-wide)
        {
            *reinterpret_cast<uint4*>(&Ks[srow][scol]) = kpre;
            s16x8 v8 = *reinterpret_cast<s16x8*>(&vpre);
            int base = (((srow >> 3) ^ g8) << 3) | (srow & 7);
            #pragma unroll
            for (int e = 0; e < 8; ++e) Vt[scol + e][base] = (u16)v8[e];
        }
        // prefetch next tile (block-wide; R10 placement)
        {
            int jg = (jt + 1) * 64 + srow;
            kpre = make_uint4(0u,0u,0u,0u); vpre = make_uint4(0u,0u,0u,0u);
            if (jg < N_) {
                size_t base = (size_t)(b * N_ + jg) * QKV_ + h * D_ + scol;
                kpre = *reinterpret_cast<const uint4*>(&qkv[base + C_]);
                vpre = *reinterpret_cast<const uint4*>(&qkv[base + 2 * C_]);
            }
        }
        __syncthreads();

        if (wactive) {
            // S = Q K^T, C-initialized to -8*log2e
            f32x4 s[4];
            #pragma unroll
            for (int bn = 0; bn < 4; ++bn)
                s[bn] = (f32x4){-SHIFT2, -SHIFT2, -SHIFT2, -SHIFT2};
            __builtin_amdgcn_s_setprio(1);
            #pragma unroll
            for (int bn = 0; bn < 4; ++bn) {
                #pragma unroll
                for (int ks = 0; ks < 2; ++ks) {
                    s16x8 kf = *reinterpret_cast<const s16x8*>(&Ks[bn * 16 + l][ks * 32 + q * 8]);
                    s[bn] = __builtin_amdgcn_mfma_f32_16x16x32_bf16(qf[ks], kf, s[bn], 0, 0, 0);
                }
            }
            __builtin_amdgcn_s_setprio(0);

            // softmax halves interleaved with PV halves
            if (jt < nJT - 1) {
                SMAX_BN(0, 0) SMAX_BN(1, 0)
                PVHALF(0)
                SMAX_BN(2, 0) SMAX_BN(3, 0)
                PVHALF(1)
            } else {
                SMAX_BN(0, 1) SMAX_BN(1, 1)
                PVHALF(0)
                SMAX_BN(2, 1) SMAX_BN(3, 1)
                PVHALF(1)
            }
        }
    }

    // epilogue: single l-reduction over the 16-lane row group, then store
    #pragma unroll
    for (int r = 0; r < 4; ++r) {
        #pragma unroll
        for (int s2 = 1; s2 < 16; s2 <<= 1)
            l_part[r] += __shfl_xor(l_part[r], s2, 64);
    }
    #pragma unroll
    for (int bn = 0; bn < 4; ++bn) {
        #pragma unroll
        for (int r = 0; r < 4; ++r) {
            int ig = i0 + wave * 16 + q * 4 + r;
            if (ig < N_) {
                float lsum = l_part[r];
                float invl = (lsum > 0.f) ? (1.0f / lsum) : 0.f;
                aout[(size_t)(b * N_ + ig) * C_ + h * D_ + bn * 16 + l] = f2bf(o_acc[bn][r] * invl);
            }
        }
    }
#undef SMAX_BN
#undef PVHALF
}

extern "C" void kernel_launch(void* const* d_in, const int* in_sizes, int n_in,
                              void* d_out, int out_size, void* d_ws, size_t ws_size,
                              hipStream_t stream)
{
    const float* x      = (const float*)d_in[0];
    const float* qkv_w  = (const float*)d_in[1];
    const float* qkv_b  = (const float*)d_in[2];
    const float* proj_w = (const float*)d_in[3];
    const float* proj_b = (const float*)d_in[4];
    const float* rpe_r  = (const float*)d_in[5];
    const float* rpe_c  = (const float*)d_in[6];
    const int*   brow   = (const int*)d_in[7];
    const int*   bcol   = (const int*)d_in[8];

    // ws layout (56.3MB < proven 67.7MB):
    //   qkv 37.8MB | aout/x_bf16 12.6MB (aliased: x_bf16 consumed by GEMM1
    //   before flash overwrites with aout — stream-ordered) | cidx 1.2MB |
    //   w1_bf16 3.5MB | w2_bf16 1.2MB
    char* p = (char*)d_ws;
    u16* qkv  = (u16*)p; p += (size_t)M_ * QKV_ * 2;
    u16* xaout = (u16*)p; p += (size_t)M_ * C_ * 2;     // x_bf16, then aout
    unsigned char* cidx = (unsigned char*)p; p += (size_t)CS_ * CS_;
    u16* w1bf = (u16*)p; p += (size_t)QKV_ * C_ * 2;
    u16* w2bf = (u16*)p;

    const long nx = (long)M_ * C_;        // 6,297,600
    const long n1 = (long)QKV_ * C_;      // 1,769,472
    const long n2 = (long)C_ * C_;        //   589,824

    // 0a) one-shot bf16 conversion of x / qkv_w / proj_w
    cvt_f32_bf16<<<(int)((nx + n1 + n2) / 8 / 256), 256, 0, stream>>>(
        x, xaout, nx, qkv_w, w1bf, n1, proj_w, w2bf, n2);

    // 0b) packed bucket table
    build_cidx<<<((CS_ * (CS_ / 4)) + 255) / 256, 256, 0, stream>>>(brow, bcol, cidx);

    // 1) qkv = x @ qkv_w^T + qkv_b ; q cols scaled by 0.125*log2e (exp2 fold)
    gemm_bt<0><<<dim3(QKV_ / 128, (M_ + 127) / 128), 256, 0, stream>>>(
        xaout, C_, w1bf, qkv_b, qkv, QKV_, M_, QKV_, C_, C_, 0.125f * LOG2E);

    // 2) MFMA flash attention (8 waves / 128 Q-rows; XCD-grouped 1-D grid)
    flash_kernel<<<dim3(8 * 12 * 9), 512, 0, stream>>>(
        qkv, rpe_r, rpe_c, cidx, xaout);

    // 3) out = aout @ proj_w^T + proj_b (bf16 in, fp32 out)
    gemm_bt<1><<<dim3(C_ / 128, (M_ + 127) / 128), 256, 0, stream>>>(
        xaout, C_, w2bf, proj_b, d_out, C_, M_, C_, C_, 0, 1.0f);
}